// Round 14
// baseline (73.681 us; speedup 1.0000x reference)
//
#include <hip/hip_runtime.h>
#include <hip/hip_bf16.h>
#include <hip/hip_fp16.h>

typedef _Float16 h8 __attribute__((ext_vector_type(8)));
typedef _Float16 h2 __attribute__((ext_vector_type(2)));
typedef unsigned short us8 __attribute__((ext_vector_type(8)));
typedef float f4 __attribute__((ext_vector_type(4)));
typedef float f16v __attribute__((ext_vector_type(16)));
typedef int i2v __attribute__((ext_vector_type(2)));

#define NH 8
#define DH 64
#define NPIX 1024
#define CIN 64
#define NBH 64
// 512 (ref scale) * log2(e): logits come out in base-2 units
#define QSCALE (512.0f * 1.44269504f)
#define LOSCALE 2048.0f
#define INV_LOSCALE (1.0f / 2048.0f)
#define DTHR 12.0f

__device__ __forceinline__ void gload_lds16(const void* g, void* lds) {
  __builtin_amdgcn_global_load_lds(
      (const __attribute__((address_space(1))) void*)g,
      (__attribute__((address_space(3))) void*)lds, 16, 0, 0);
}

__device__ __forceinline__ float fexp2(float x) {
#if __has_builtin(__builtin_amdgcn_exp2f)
  return __builtin_amdgcn_exp2f(x);
#else
  return exp2f(x);
#endif
}

__device__ __forceinline__ unsigned pk16(float a, float b) {
  auto r = __builtin_amdgcn_cvt_pkrtz(a, b);   // __fp16 ext_vector(2)
  union { decltype(r) h; unsigned u; } x;
  x.h = r;
  return x.u;
}

// ---------------- QKV projection via compensated fp16 MFMA ----------------
__global__ __launch_bounds__(256) void qkv_mfma(
    const float* __restrict__ x, const float* __restrict__ wqkv,
    _Float16* __restrict__ Qh, _Float16* __restrict__ Ql,
    _Float16* __restrict__ Kh, _Float16* __restrict__ Kl,
    _Float16* __restrict__ Vv) {
  __shared__ __align__(16) char QS[49152];
  char* Wh = QS;
  char* Wl = QS + 16384;
  char* Xh = QS + 32768;
  char* Xl = QS + 40960;
  char* Thi = QS;              // epilogue reuse: [64 p][128 o] f16 = 16KB
  char* Tlo = QS + 16384;

  const int tid = threadIdx.x;
  const int lane = tid & 63;
  const int w = tid >> 6;
  const int c = lane & 15;
  const int g = lane >> 4;
  const int o0 = blockIdx.x * 128;
  const int p0 = blockIdx.y * 64;
  const int b = blockIdx.z;

  #pragma unroll
  for (int it = 0; it < 4; ++it) {
    int task = tid + it * 256;
    int oct = task & 7, o = task >> 3;
    const f4* wr = (const f4*)(wqkv + (size_t)(o0 + o) * CIN + oct * 8);
    f4 wa = wr[0], wb = wr[1];
    h8 hi, lo;
    #pragma unroll
    for (int e = 0; e < 8; ++e) {
      float v = e < 4 ? wa[e] : wb[e - 4];
      _Float16 h = (_Float16)v;
      hi[e] = h;
      lo[e] = (_Float16)((v - (float)h) * LOSCALE);
    }
    int byo = o * 128 + ((oct ^ (o & 7)) << 4);
    *(h8*)(Wh + byo) = hi;
    *(h8*)(Wl + byo) = lo;
  }
  {
    int kp = tid & 31;      // c-pair: channels 2kp, 2kp+1
    int pgrp = tid >> 5;    // p-octet 0..7
    const float* xr0 = x + ((size_t)b * CIN + 2 * kp) * NPIX + p0 + pgrp * 8;
    const float* xr1 = xr0 + NPIX;
    f4 a0 = *(const f4*)xr0, a1 = *(const f4*)(xr0 + 4);
    f4 b0 = *(const f4*)xr1, b1 = *(const f4*)(xr1 + 4);
    int oct = kp >> 2;
    int slot4 = (kp & 3) * 4;
    #pragma unroll
    for (int e = 0; e < 8; ++e) {
      float v0 = e < 4 ? a0[e] : a1[e - 4];
      float v1 = e < 4 ? b0[e] : b1[e - 4];
      _Float16 h0 = (_Float16)v0, h1 = (_Float16)v1;
      float l0f = (v0 - (float)h0) * LOSCALE;
      float l1f = (v1 - (float)h1) * LOSCALE;
      int p = pgrp * 8 + e;
      int byo = p * 128 + ((oct ^ (p & 7)) << 4) + slot4;
      union { h2 h; unsigned u; } uh, ul;
      uh.h[0] = h0; uh.h[1] = h1;
      ul.h[0] = (_Float16)l0f; ul.h[1] = (_Float16)l1f;
      *(unsigned*)(Xh + byo) = uh.u;
      *(unsigned*)(Xl + byo) = ul.u;
    }
  }
  __syncthreads();

  f4 zf = {0.f, 0.f, 0.f, 0.f};
  f4 acc[2][4], cor[2][4];
  #pragma unroll
  for (int oi = 0; oi < 2; ++oi)
    #pragma unroll
    for (int pi = 0; pi < 4; ++pi) { acc[oi][pi] = zf; cor[oi][pi] = zf; }

  const int ob = w * 32;
  #pragma unroll
  for (int kh = 0; kh < 2; ++kh) {
    h8 ah[2], al[2], bh[4], bl[4];
    #pragma unroll
    for (int oi = 0; oi < 2; ++oi) {
      int orow = ob + ((c >> 2) << 3) + (c & 3) + oi * 4;
      int ch = (((kh * 4 + g) ^ (orow & 7)) << 4);
      ah[oi] = *(const h8*)(Wh + orow * 128 + ch);
      al[oi] = *(const h8*)(Wl + orow * 128 + ch);
    }
    #pragma unroll
    for (int pi = 0; pi < 4; ++pi) {
      int prow = pi * 16 + c;
      int ch = (((kh * 4 + g) ^ (prow & 7)) << 4);
      bh[pi] = *(const h8*)(Xh + prow * 128 + ch);
      bl[pi] = *(const h8*)(Xl + prow * 128 + ch);
    }
    __builtin_amdgcn_s_setprio(1);
    #pragma unroll
    for (int oi = 0; oi < 2; ++oi)
      #pragma unroll
      for (int pi = 0; pi < 4; ++pi) {
        acc[oi][pi] = __builtin_amdgcn_mfma_f32_16x16x32_f16(ah[oi], bh[pi], acc[oi][pi], 0, 0, 0);
        cor[oi][pi] = __builtin_amdgcn_mfma_f32_16x16x32_f16(ah[oi], bl[pi], cor[oi][pi], 0, 0, 0);
        cor[oi][pi] = __builtin_amdgcn_mfma_f32_16x16x32_f16(al[oi], bh[pi], cor[oi][pi], 0, 0, 0);
      }
    __builtin_amdgcn_s_setprio(0);
  }

  const int part = o0 >> 9;
  const float scl = part == 0 ? QSCALE : 1.0f;
  _Float16* dsth = part == 0 ? Qh : (part == 1 ? Kh : Vv);
  _Float16* dstl = part == 0 ? Ql : (part == 1 ? Kl : nullptr);

  __syncthreads();   // all LDS operand reads done; reuse QS for output tile
  {
    const int chunk = 4 * w + g;
    #pragma unroll
    for (int pi = 0; pi < 4; ++pi) {
      int p = pi * 16 + c;
      h8 hv, lv;
      #pragma unroll
      for (int oi = 0; oi < 2; ++oi)
        #pragma unroll
        for (int reg = 0; reg < 4; ++reg) {
          float v = (acc[oi][pi][reg] + cor[oi][pi][reg] * INV_LOSCALE) * scl;
          _Float16 hh = (_Float16)v;
          hv[oi * 4 + reg] = hh;
          lv[oi * 4 + reg] = (_Float16)(v - (float)hh);   // UNSCALED residual
        }
      int byo = p * 256 + ((chunk ^ (p & 15)) << 4);
      *(h8*)(Thi + byo) = hv;
      if (dstl) *(h8*)(Tlo + byo) = lv;
    }
  }
  __syncthreads();
  #pragma unroll
  for (int it = 0; it < 4; ++it) {
    int task = tid + it * 256;
    int p = task >> 4;
    int ck = task & 15;
    int byo = p * 256 + ((ck ^ (p & 15)) << 4);
    int o = o0 + ck * 8;
    int h = (o >> 6) & 7;
    int d = o & 63;
    size_t off = (((size_t)(b * NH + h)) * NPIX + p0 + p) * DH + d;
    h8 v = *(const h8*)(Thi + byo);
    *(h8*)(dsth + off) = v;
    if (dstl) {
      h8 v2 = *(const h8*)(Tlo + byo);
      *(h8*)(dstl + off) = v2;
    }
  }
}

// ---------------- fused MFMA attention: 32x32x16, skewed pipeline --------
// Wave w owns rows i = w*32 + (lane&31); k/j slot = lane>>5.
// LDS (56KB): KH[2] 0..16K | KL[2] 16K..32K | VB[2] 32K..48K |
//             LHc 48K..56K ([16 t][128 rows][2] fp16).
// Pipeline: QK(t+1) issued before finish(t); K prefetch 2 tiles ahead.
__global__ __launch_bounds__(256, 2) void attn_mfma(
    const _Float16* __restrict__ Qh, const _Float16* __restrict__ Ql,
    const _Float16* __restrict__ Kh, const _Float16* __restrict__ Kl,
    const _Float16* __restrict__ V,
    const float* __restrict__ rel_h, const float* __restrict__ rel_w,
    float* __restrict__ out) {
  __shared__ __align__(16) char SMem[57344];
  _Float16* LHc = (_Float16*)(SMem + 49152);  // [16 t][128 rows][2] fp16
  _Float16* LWT = (_Float16*)(SMem + 32768);  // prologue temp [128][64]
  float* OT = (float*)SMem;                   // epilogue [64][128] f32
  char* kb0 = SMem;
  char* kb1 = SMem + 8192;
  char* klb0 = SMem + 16384;
  char* klb1 = SMem + 24576;
  char* vb0 = SMem + 32768;
  char* vb1 = SMem + 40960;

  const int tid = threadIdx.x;
  const int lane = tid & 63;
  const int w = tid >> 6;
  const int wu = __builtin_amdgcn_readfirstlane(w);
  const int c = lane & 15;
  const int g = lane >> 4;
  const int il = lane & 31;
  const int hi = lane >> 5;
  const int jp = tid & 31, dd = tid >> 5;
  const int bx = blockIdx.x;
  const int bh = ((bx & 7) << 3) | ((bx >> 3) & 7);
  const int i0 = (bx >> 6) << 7;
  const int swl = (il & 7);

  const _Float16* Qhg = Qh + (size_t)bh * NPIX * DH;
  const _Float16* Qlg = Ql + (size_t)bh * NPIX * DH;
  const _Float16* Khg = Kh + (size_t)bh * NPIX * DH;
  const _Float16* Klg = Kl + (size_t)bh * NPIX * DH;
  const _Float16* Vg  = V  + (size_t)bh * NPIX * DH;

  // prologue Q fragments (16x16 B operand)
  const h8* Qr0h = (const h8*)(Qhg + (size_t)(i0 + w * 32 + c) * DH);
  const h8* Qr0l = (const h8*)(Qlg + (size_t)(i0 + w * 32 + c) * DH);
  const h8* Qr1h = (const h8*)(Qhg + (size_t)(i0 + w * 32 + 16 + c) * DH);
  const h8* Qr1l = (const h8*)(Qlg + (size_t)(i0 + w * 32 + 16 + c) * DH);
  h8 q0h[2] = {Qr0h[g], Qr0h[4 + g]};
  h8 q0l[2] = {Qr0l[g], Qr0l[4 + g]};
  h8 q1h[2] = {Qr1h[g], Qr1h[4 + g]};
  h8 q1l[2] = {Qr1l[g], Qr1l[4 + g]};

  // K staging offsets (pre-swizzled global source, linear LDS dest)
  const int s0i = wu * 128 + lane;
  const int s1i = s0i + 64;
  const int ko0 = (s0i >> 3) * 128 + (((s0i & 7) ^ ((s0i >> 3) & 7)) << 4);
  const int ko1 = (s1i >> 3) * 128 + (((s1i & 7) ^ ((s1i >> 3) & 7)) << 4);

  // ---- stage rel tables: rel_h -> kb area, rel_w -> klb area ----
  #pragma unroll
  for (int it = 0; it < 2; ++it) {
    int task = tid + it * 256;
    int oct = task & 7, s = task >> 3;
    int ss = s < 63 ? s : 62;
    const float* sh = rel_h + (size_t)ss * DH + oct * 8;
    const float* sw = rel_w + (size_t)ss * DH + oct * 8;
    h8 hh, ww;
    #pragma unroll
    for (int e = 0; e < 8; ++e) {
      hh[e] = (_Float16)sh[e];
      ww[e] = (_Float16)sw[e];
    }
    int byo = s * 128 + ((oct ^ (s & 7)) << 4);
    *(h8*)(SMem + byo) = hh;
    *(h8*)(SMem + 16384 + byo) = ww;
  }
  __syncthreads();

  // ---- lh/lw tables via swapped 16x16 MFMA (lo folded into same acc) ----
  const int yi = (i0 + w * 32) >> 5;
  f4 zf = {0.f, 0.f, 0.f, 0.f};
  #pragma unroll
  for (int rs = 0; rs < 2; ++rs) {
    f4 lhD[4], lwD[4];
    #pragma unroll
    for (int st = 0; st < 4; ++st) { lhD[st] = zf; lwD[st] = zf; }
    #pragma unroll
    for (int kh = 0; kh < 2; ++kh) {
      h8 bq = rs ? q1h[kh] : q0h[kh];
      h8 bl = rs ? q1l[kh] : q0l[kh];
      #pragma unroll
      for (int st = 0; st < 4; ++st) {
        int srow = st * 16 + c;
        int chb = srow * 128 + (((kh * 4 + g) ^ (srow & 7)) << 4);
        h8 ra = *(const h8*)(SMem + chb);
        h8 wa = *(const h8*)(SMem + 16384 + chb);
        lhD[st] = __builtin_amdgcn_mfma_f32_16x16x32_f16(ra, bq, lhD[st], 0, 0, 0);
        lhD[st] = __builtin_amdgcn_mfma_f32_16x16x32_f16(ra, bl, lhD[st], 0, 0, 0);
        lwD[st] = __builtin_amdgcn_mfma_f32_16x16x32_f16(wa, bq, lwD[st], 0, 0, 0);
        lwD[st] = __builtin_amdgcn_mfma_f32_16x16x32_f16(wa, bl, lwD[st], 0, 0, 0);
      }
    }
    int lrow = w * 32 + rs * 16 + c;
    #pragma unroll
    for (int st = 0; st < 4; ++st)
      #pragma unroll
      for (int reg = 0; reg < 4; ++reg) {
        int s = st * 16 + 4 * g + reg;
        int k = s - 31 + yi;
        if (k >= 0 && k < 32)
          LHc[(k >> 1) * 256 + lrow * 2 + (k & 1)] = (_Float16)lhD[st][reg];
        LWT[lrow * 64 + s] = (_Float16)lwD[st][reg];
      }
  }
  __syncthreads();

  // lwp[reg]: lw[i][31 + jl(reg) - il], jl = (reg&3)+8*(reg>>2)+4*hi
  float lwp[16];
  {
    int r = w * 32 + il;
    #pragma unroll
    for (int reg = 0; reg < 16; ++reg) {
      int jl = (reg & 3) + 8 * (reg >> 2) + 4 * hi;
      lwp[reg] = (float)LWT[r * 64 + 31 + jl - il];
    }
  }
  // main-loop Q fragments (32x32 B operand: col = il, k-slot = hi)
  const h8* Qmh = (const h8*)(Qhg + (size_t)(i0 + w * 32 + il) * DH);
  const h8* Qml = (const h8*)(Qlg + (size_t)(i0 + w * 32 + il) * DH);
  h8 qmh[4], qml[4];
  #pragma unroll
  for (int kb = 0; kb < 4; ++kb) {
    qmh[kb] = Qmh[2 * kb + hi];
    qml[kb] = Qml[2 * kb + hi];
  }
  __syncthreads();

  float m_s = -1e30f, lp = 0.f;
  f16v O0, O1, SA0, SA1, SB0, SB1;
  #pragma unroll
  for (int e = 0; e < 16; ++e) { O0[e] = 0.f; O1[e] = 0.f; }
  h8 vr0, vr1;

  // QK^T for one tile from given buffers
  auto qk = [&](const char* Kc, const char* KLc, f16v& T0, f16v& T1) {
    #pragma unroll
    for (int e = 0; e < 16; ++e) { T0[e] = 0.f; T1[e] = 0.f; }
    #pragma unroll
    for (int kb = 0; kb < 4; ++kb) {
      int chb0 = il * 128 + (((2 * kb + hi) ^ swl) << 4);
      int chb1 = chb0 + 32 * 128;
      h8 a0h = *(const h8*)(Kc + chb0);
      h8 a0l = *(const h8*)(KLc + chb0);
      h8 a1h = *(const h8*)(Kc + chb1);
      h8 a1l = *(const h8*)(KLc + chb1);
      __builtin_amdgcn_s_setprio(1);
      T0 = __builtin_amdgcn_mfma_f32_32x32x16_f16(a0h, qmh[kb], T0, 0, 0, 0);
      T0 = __builtin_amdgcn_mfma_f32_32x32x16_f16(a0l, qmh[kb], T0, 0, 0, 0);
      T0 = __builtin_amdgcn_mfma_f32_32x32x16_f16(a0h, qml[kb], T0, 0, 0, 0);
      T1 = __builtin_amdgcn_mfma_f32_32x32x16_f16(a1h, qmh[kb], T1, 0, 0, 0);
      T1 = __builtin_amdgcn_mfma_f32_32x32x16_f16(a1l, qmh[kb], T1, 0, 0, 0);
      T1 = __builtin_amdgcn_mfma_f32_32x32x16_f16(a1h, qml[kb], T1, 0, 0, 0);
      __builtin_amdgcn_s_setprio(0);
    }
  };

  // bias + online softmax + in-register P fragments (T12)
  auto finish = [&](int t, f16v& S0, f16v& S1, h8* fr) {
    int r = w * 32 + il;
    h2 lhu = *(const h2*)(LHc + t * 256 + r * 2);
    float lh0 = (float)lhu[0], lh1 = (float)lhu[1];
    #pragma unroll
    for (int reg = 0; reg < 16; ++reg) {
      S0[reg] += lwp[reg] + lh0;
      S1[reg] += lwp[reg] + lh1;
    }
    float v8[8];
    #pragma unroll
    for (int e = 0; e < 8; ++e)
      v8[e] = fmaxf(fmaxf(S0[e], S0[e + 8]), fmaxf(S1[e], S1[e + 8]));
    float w0 = fmaxf(fmaxf(v8[0], v8[1]), fmaxf(v8[2], v8[3]));
    float w1 = fmaxf(fmaxf(v8[4], v8[5]), fmaxf(v8[6], v8[7]));
    float mx = fmaxf(w0, w1);
    mx = fmaxf(mx, __shfl_xor(mx, 32, 64));
    bool sk = mx <= m_s + DTHR;      // T13 defer-max
    if (!__all(sk)) {
      float mn = fmaxf(m_s, mx);
      float corr = fexp2(m_s - mn);
      m_s = mn;
      lp *= corr;
      #pragma unroll
      for (int e = 0; e < 16; ++e) { O0[e] *= corr; O1[e] *= corr; }
    }
    float pv0[16], pv1[16];
    #pragma unroll
    for (int e = 0; e < 16; ++e) {
      pv0[e] = fexp2(S0[e] - m_s);
      pv1[e] = fexp2(S1[e] - m_s);
    }
    f4 ps = zf;
    #pragma unroll
    for (int e = 0; e < 16; e += 4) {
      ps[0] += pv0[e] + pv1[e];
      ps[1] += pv0[e + 1] + pv1[e + 1];
      ps[2] += pv0[e + 2] + pv1[e + 2];
      ps[3] += pv0[e + 3] + pv1[e + 3];
    }
    lp += (ps[0] + ps[1]) + (ps[2] + ps[3]);
    #pragma unroll
    for (int jkb = 0; jkb < 4; ++jkb) {
      const float* pv = (jkb < 2) ? pv0 : pv1;
      int base = (jkb & 1) * 8;
      unsigned x01 = pk16(pv[base + 0], pv[base + 1]);
      unsigned x23 = pk16(pv[base + 2], pv[base + 3]);
      unsigned y01 = pk16(pv[base + 4], pv[base + 5]);
      unsigned y23 = pk16(pv[base + 6], pv[base + 7]);
      i2v r1 = __builtin_amdgcn_permlane32_swap((int)x01, (int)y01, false, false);
      i2v r2 = __builtin_amdgcn_permlane32_swap((int)x23, (int)y23, false, false);
      union { unsigned u[4]; h8 h; } fu;
      fu.u[0] = (unsigned)r1[0];
      fu.u[1] = (unsigned)r2[0];
      fu.u[2] = (unsigned)r1[1];
      fu.u[3] = (unsigned)r2[1];
      fr[jkb] = fu.h;
    }
  };

  auto pv_step = [&](const char* Vc, const h8* fr) {
    #pragma unroll
    for (int jkb = 0; jkb < 4; ++jkb) {
      int och = (((2 * jkb + hi) ^ swl) << 4);
      __builtin_amdgcn_s_setprio(1);
      h8 av0 = *(const h8*)(Vc + il * 128 + och);
      h8 av1 = *(const h8*)(Vc + (32 + il) * 128 + och);
      O0 = __builtin_amdgcn_mfma_f32_32x32x16_f16(av0, fr[jkb], O0, 0, 0, 0);
      O1 = __builtin_amdgcn_mfma_f32_32x32x16_f16(av1, fr[jkb], O1, 0, 0, 0);
      __builtin_amdgcn_s_setprio(0);
    }
  };

  auto vwrite = [&](char* vb) {
    us8 u0 = *(const us8*)&vr0, u1 = *(const us8*)&vr1;
    #pragma unroll
    for (int e = 0; e < 8; ++e) {
      int d = dd * 8 + e;
      unsigned val = (unsigned)u0[e] | ((unsigned)u1[e] << 16);
      *(unsigned*)(vb + d * 128 + (((jp >> 2) ^ (d & 7)) << 4) + (jp & 3) * 4) = val;
    }
  };

  // ---- pipeline prologue: K(0)->kb0, K(1)->kb1 (DMA); V(0)->regs ----
  {
    gload_lds16((const char*)Khg + ko0, kb0 + wu * 2048);
    gload_lds16((const char*)Khg + ko1, kb0 + wu * 2048 + 1024);
    gload_lds16((const char*)Klg + ko0, klb0 + wu * 2048);
    gload_lds16((const char*)Klg + ko1, klb0 + wu * 2048 + 1024);
    gload_lds16((const char*)Khg + 8192 + ko0, kb1 + wu * 2048);
    gload_lds16((const char*)Khg + 8192 + ko1, kb1 + wu * 2048 + 1024);
    gload_lds16((const char*)Klg + 8192 + ko0, klb1 + wu * 2048);
    gload_lds16((const char*)Klg + 8192 + ko1, klb1 + wu * 2048 + 1024);
    const h8* vrp = (const h8*)(Vg + (size_t)(2 * jp) * DH);
    vr0 = vrp[dd];
    vr1 = vrp[8 + dd];
  }
  __syncthreads();              // K0,K1 in LDS; V0 in regs
  vwrite(vb0);                  // V(0) -> vb0
  {
    const h8* vrp = (const h8*)(Vg + (size_t)(64 + 2 * jp) * DH);
    vr0 = vrp[dd];
    vr1 = vrp[8 + dd];          // V(1) -> regs
  }
  qk(kb0, klb0, SA0, SA1);      // S(0)
  __syncthreads();              // vb0 visible; all waves done reading kb0

  // ---- skewed main loop: one barrier per tile ----
  #pragma unroll 1
  for (int tp = 0; tp < 8; ++tp) {
    // ---- even tile t = 2*tp: Sc=SA, Sn=SB ----
    {
      const int t = 2 * tp;
      if (t < 14) {             // DMA K(t+2) -> kbuf[t&1]=kb0
        const char* kg  = (const char*)Khg + (size_t)(t + 2) * 8192;
        const char* klg = (const char*)Klg + (size_t)(t + 2) * 8192;
        gload_lds16(kg + ko0, kb0 + wu * 2048);
        gload_lds16(kg + ko1, kb0 + wu * 2048 + 1024);
        gload_lds16(klg + ko0, klb0 + wu * 2048);
        gload_lds16(klg + ko1, klb0 + wu * 2048 + 1024);
      }
      if (t < 15) vwrite(vb1);  // V(t+1) -> vbuf[(t+1)&1]
      if (t < 14) {             // V(t+2) -> regs
        const h8* vrp = (const h8*)(Vg + (size_t)((t + 2) * 64 + 2 * jp) * DH);
        vr0 = vrp[dd];
        vr1 = vrp[8 + dd];
      }
      if (t < 15) qk(kb1, klb1, SB0, SB1);   // S(t+1), overlaps finish(t)
      h8 fr[4];
      finish(t, SA0, SA1, fr);
      pv_step(vb0, fr);
      __syncthreads();
    }
    // ---- odd tile t = 2*tp+1: Sc=SB, Sn=SA ----
    {
      const int t = 2 * tp + 1;
      if (t < 14) {             // DMA K(t+2) -> kbuf[t&1]=kb1
        const char* kg  = (const char*)Khg + (size_t)(t + 2) * 8192;
        const char* klg = (const char*)Klg + (size_t)(t + 2) * 8192;
        gload_lds16(kg + ko0, kb1 + wu * 2048);
        gload_lds16(kg + ko1, kb1 + wu * 2048 + 1024);
        gload_lds16(klg + ko0, klb1 + wu * 2048);
        gload_lds16(klg + ko1, klb1 + wu * 2048 + 1024);
      }
      if (t < 15) vwrite(vb0);  // V(t+1) -> vbuf[(t+1)&1]
      if (t < 14) {             // V(t+2) -> regs
        const h8* vrp = (const h8*)(Vg + (size_t)((t + 2) * 64 + 2 * jp) * DH);
        vr0 = vrp[dd];
        vr1 = vrp[8 + dd];
      }
      if (t < 15) qk(kb0, klb0, SA0, SA1);   // S(t+1), overlaps finish(t)
      h8 fr[4];
      finish(t, SB0, SB1, fr);
      pv_step(vb1, fr);
      __syncthreads();
    }
  }

  // ---- epilogue: reduce l across hi, normalize, transpose, store ----
  float lt = lp + __shfl_xor(lp, 32, 64);
  float rr = __builtin_amdgcn_rcpf(lt);
  {
    int r = w * 32 + il;
    #pragma unroll
    for (int reg = 0; reg < 16; ++reg) {
      int dl = (reg & 3) + 8 * (reg >> 2) + 4 * hi;
      int d0 = dl;
      int d1 = 32 + dl;
      OT[d0 * 128 + (r ^ ((d0 & 7) << 3))] = O0[reg] * rr;
      OT[d1 * 128 + (r ^ ((d1 & 7) << 3))] = O1[reg] * rr;
    }
  }
  __syncthreads();
  #pragma unroll
  for (int it = 0; it < 8; ++it) {
    int task = tid + it * 256;
    int rq = task & 31, d = task >> 5;
    f4 vv = *(const f4*)&OT[d * 128 + ((rq * 4) ^ ((d & 7) << 3))];
    *(f4*)(out + (((size_t)bh * 64 + d) << 10) + i0 + rq * 4) = vv;
  }
}

extern "C" void kernel_launch(void* const* d_in, const int* in_sizes, int n_in,
                              void* d_out, int out_size, void* d_ws, size_t ws_size,
                              hipStream_t stream) {
  const float* x  = (const float*)d_in[0];
  const float* wq = (const float*)d_in[1];
  const float* rh = (const float*)d_in[2];
  const float* rw = (const float*)d_in[3];
  float* out = (float*)d_out;

  const size_t sz = (size_t)NBH * NPIX * DH;
  _Float16* Qh = (_Float16*)d_ws;
  _Float16* Ql = Qh + sz;
  _Float16* Kh = Ql + sz;
  _Float16* Kl = Kh + sz;
  _Float16* V  = Kl + sz;

  qkv_mfma<<<dim3(12, 16, 8), 256, 0, stream>>>(x, wq, Qh, Ql, Kh, Kl, V);
  attn_mfma<<<dim3(512), 256, 0, stream>>>(Qh, Ql, Kh, Kl, V, rh, rw, out);
}

// Round 15
// 71.756 us; speedup vs baseline: 1.0268x; 1.0268x over previous
//
#include <hip/hip_runtime.h>
#include <hip/hip_bf16.h>
#include <hip/hip_fp16.h>

typedef _Float16 h8 __attribute__((ext_vector_type(8)));
typedef _Float16 h2 __attribute__((ext_vector_type(2)));
typedef unsigned short us8 __attribute__((ext_vector_type(8)));
typedef float f4 __attribute__((ext_vector_type(4)));
typedef float f16v __attribute__((ext_vector_type(16)));
typedef int i2v __attribute__((ext_vector_type(2)));

#define NH 8
#define DH 64
#define NPIX 1024
#define CIN 64
#define NBH 64
// 512 (ref scale) * log2(e): logits come out in base-2 units
#define QSCALE (512.0f * 1.44269504f)
#define LOSCALE 2048.0f
#define INV_LOSCALE (1.0f / 2048.0f)
#define DTHR 12.0f

__device__ __forceinline__ void gload_lds16(const void* g, void* lds) {
  __builtin_amdgcn_global_load_lds(
      (const __attribute__((address_space(1))) void*)g,
      (__attribute__((address_space(3))) void*)lds, 16, 0, 0);
}

__device__ __forceinline__ float fexp2(float x) {
#if __has_builtin(__builtin_amdgcn_exp2f)
  return __builtin_amdgcn_exp2f(x);
#else
  return exp2f(x);
#endif
}

__device__ __forceinline__ unsigned pk16(float a, float b) {
  auto r = __builtin_amdgcn_cvt_pkrtz(a, b);   // __fp16 ext_vector(2)
  union { decltype(r) h; unsigned u; } x;
  x.h = r;
  return x.u;
}

// ---------------- QKV projection via compensated fp16 MFMA ----------------
__global__ __launch_bounds__(256) void qkv_mfma(
    const float* __restrict__ x, const float* __restrict__ wqkv,
    _Float16* __restrict__ Qh, _Float16* __restrict__ Ql,
    _Float16* __restrict__ Kh, _Float16* __restrict__ Kl,
    _Float16* __restrict__ Vv) {
  __shared__ __align__(16) char QS[49152];
  char* Wh = QS;
  char* Wl = QS + 16384;
  char* Xh = QS + 32768;
  char* Xl = QS + 40960;
  char* Thi = QS;              // epilogue reuse: [64 p][128 o] f16 = 16KB
  char* Tlo = QS + 16384;

  const int tid = threadIdx.x;
  const int lane = tid & 63;
  const int w = tid >> 6;
  const int c = lane & 15;
  const int g = lane >> 4;
  const int o0 = blockIdx.x * 128;
  const int p0 = blockIdx.y * 64;
  const int b = blockIdx.z;

  #pragma unroll
  for (int it = 0; it < 4; ++it) {
    int task = tid + it * 256;
    int oct = task & 7, o = task >> 3;
    const f4* wr = (const f4*)(wqkv + (size_t)(o0 + o) * CIN + oct * 8);
    f4 wa = wr[0], wb = wr[1];
    h8 hi, lo;
    #pragma unroll
    for (int e = 0; e < 8; ++e) {
      float v = e < 4 ? wa[e] : wb[e - 4];
      _Float16 h = (_Float16)v;
      hi[e] = h;
      lo[e] = (_Float16)((v - (float)h) * LOSCALE);
    }
    int byo = o * 128 + ((oct ^ (o & 7)) << 4);
    *(h8*)(Wh + byo) = hi;
    *(h8*)(Wl + byo) = lo;
  }
  {
    int kp = tid & 31;      // c-pair: channels 2kp, 2kp+1
    int pgrp = tid >> 5;    // p-octet 0..7
    const float* xr0 = x + ((size_t)b * CIN + 2 * kp) * NPIX + p0 + pgrp * 8;
    const float* xr1 = xr0 + NPIX;
    f4 a0 = *(const f4*)xr0, a1 = *(const f4*)(xr0 + 4);
    f4 b0 = *(const f4*)xr1, b1 = *(const f4*)(xr1 + 4);
    int oct = kp >> 2;
    int slot4 = (kp & 3) * 4;
    #pragma unroll
    for (int e = 0; e < 8; ++e) {
      float v0 = e < 4 ? a0[e] : a1[e - 4];
      float v1 = e < 4 ? b0[e] : b1[e - 4];
      _Float16 h0 = (_Float16)v0, h1 = (_Float16)v1;
      float l0f = (v0 - (float)h0) * LOSCALE;
      float l1f = (v1 - (float)h1) * LOSCALE;
      int p = pgrp * 8 + e;
      int byo = p * 128 + ((oct ^ (p & 7)) << 4) + slot4;
      union { h2 h; unsigned u; } uh, ul;
      uh.h[0] = h0; uh.h[1] = h1;
      ul.h[0] = (_Float16)l0f; ul.h[1] = (_Float16)l1f;
      *(unsigned*)(Xh + byo) = uh.u;
      *(unsigned*)(Xl + byo) = ul.u;
    }
  }
  __syncthreads();

  f4 zf = {0.f, 0.f, 0.f, 0.f};
  f4 acc[2][4], cor[2][4];
  #pragma unroll
  for (int oi = 0; oi < 2; ++oi)
    #pragma unroll
    for (int pi = 0; pi < 4; ++pi) { acc[oi][pi] = zf; cor[oi][pi] = zf; }

  const int ob = w * 32;
  #pragma unroll
  for (int kh = 0; kh < 2; ++kh) {
    h8 ah[2], al[2], bh[4], bl[4];
    #pragma unroll
    for (int oi = 0; oi < 2; ++oi) {
      int orow = ob + ((c >> 2) << 3) + (c & 3) + oi * 4;
      int ch = (((kh * 4 + g) ^ (orow & 7)) << 4);
      ah[oi] = *(const h8*)(Wh + orow * 128 + ch);
      al[oi] = *(const h8*)(Wl + orow * 128 + ch);
    }
    #pragma unroll
    for (int pi = 0; pi < 4; ++pi) {
      int prow = pi * 16 + c;
      int ch = (((kh * 4 + g) ^ (prow & 7)) << 4);
      bh[pi] = *(const h8*)(Xh + prow * 128 + ch);
      bl[pi] = *(const h8*)(Xl + prow * 128 + ch);
    }
    __builtin_amdgcn_s_setprio(1);
    #pragma unroll
    for (int oi = 0; oi < 2; ++oi)
      #pragma unroll
      for (int pi = 0; pi < 4; ++pi) {
        acc[oi][pi] = __builtin_amdgcn_mfma_f32_16x16x32_f16(ah[oi], bh[pi], acc[oi][pi], 0, 0, 0);
        cor[oi][pi] = __builtin_amdgcn_mfma_f32_16x16x32_f16(ah[oi], bl[pi], cor[oi][pi], 0, 0, 0);
        cor[oi][pi] = __builtin_amdgcn_mfma_f32_16x16x32_f16(al[oi], bh[pi], cor[oi][pi], 0, 0, 0);
      }
    __builtin_amdgcn_s_setprio(0);
  }

  const int part = o0 >> 9;
  const float scl = part == 0 ? QSCALE : 1.0f;
  _Float16* dsth = part == 0 ? Qh : (part == 1 ? Kh : Vv);
  _Float16* dstl = part == 0 ? Ql : (part == 1 ? Kl : nullptr);

  __syncthreads();   // all LDS operand reads done; reuse QS for output tile
  {
    const int chunk = 4 * w + g;
    #pragma unroll
    for (int pi = 0; pi < 4; ++pi) {
      int p = pi * 16 + c;
      h8 hv, lv;
      #pragma unroll
      for (int oi = 0; oi < 2; ++oi)
        #pragma unroll
        for (int reg = 0; reg < 4; ++reg) {
          float v = (acc[oi][pi][reg] + cor[oi][pi][reg] * INV_LOSCALE) * scl;
          _Float16 hh = (_Float16)v;
          hv[oi * 4 + reg] = hh;
          lv[oi * 4 + reg] = (_Float16)(v - (float)hh);   // UNSCALED residual
        }
      int byo = p * 256 + ((chunk ^ (p & 15)) << 4);
      *(h8*)(Thi + byo) = hv;
      if (dstl) *(h8*)(Tlo + byo) = lv;
    }
  }
  __syncthreads();
  #pragma unroll
  for (int it = 0; it < 4; ++it) {
    int task = tid + it * 256;
    int p = task >> 4;
    int ck = task & 15;
    int byo = p * 256 + ((ck ^ (p & 15)) << 4);
    int o = o0 + ck * 8;
    int h = (o >> 6) & 7;
    int d = o & 63;
    size_t off = (((size_t)(b * NH + h)) * NPIX + p0 + p) * DH + d;
    h8 v = *(const h8*)(Thi + byo);
    *(h8*)(dsth + off) = v;
    if (dstl) {
      h8 v2 = *(const h8*)(Tlo + byo);
      *(h8*)(dstl + off) = v2;
    }
  }
}

// ---------------- fused MFMA attention: 32x32x16, 48KB LDS, lh in regs ----
// Wave w owns rows i = w*32 + (lane&31); k/j slot = lane>>5.
// LDS (48KB): KH[2] 0..16K | KL[2] 16K..32K | VB[2] 32K..48K.
// lh bias table lives in 16 packed-h2 VGPRs (full-unrolled loop).
__global__ __launch_bounds__(256, 3) void attn_mfma(
    const _Float16* __restrict__ Qh, const _Float16* __restrict__ Ql,
    const _Float16* __restrict__ Kh, const _Float16* __restrict__ Kl,
    const _Float16* __restrict__ V,
    const float* __restrict__ rel_h, const float* __restrict__ rel_w,
    float* __restrict__ out) {
  __shared__ __align__(16) char SMem[49152];
  _Float16* LWT = (_Float16*)SMem;             // prologue temp [128][64] 16KB
  _Float16* LHt = (_Float16*)(SMem + 16384);   // prologue temp [128][32] 8KB
  float* OT = (float*)SMem;                    // epilogue [64][128] f32 32KB

  const int tid = threadIdx.x;
  const int lane = tid & 63;
  const int w = tid >> 6;
  const int wu = __builtin_amdgcn_readfirstlane(w);
  const int c = lane & 15;
  const int g = lane >> 4;
  const int il = lane & 31;
  const int hi = lane >> 5;
  const int jp = tid & 31, dd = tid >> 5;
  const int bx = blockIdx.x;
  const int bh = ((bx & 7) << 3) | ((bx >> 3) & 7);
  const int i0 = (bx >> 6) << 7;
  const int swl = (il & 7);

  const _Float16* Qhg = Qh + (size_t)bh * NPIX * DH;
  const _Float16* Qlg = Ql + (size_t)bh * NPIX * DH;
  const _Float16* Khg = Kh + (size_t)bh * NPIX * DH;
  const _Float16* Klg = Kl + (size_t)bh * NPIX * DH;
  const _Float16* Vg  = V  + (size_t)bh * NPIX * DH;

  // prologue Q fragments (16x16 B operand)
  const h8* Qr0h = (const h8*)(Qhg + (size_t)(i0 + w * 32 + c) * DH);
  const h8* Qr0l = (const h8*)(Qlg + (size_t)(i0 + w * 32 + c) * DH);
  const h8* Qr1h = (const h8*)(Qhg + (size_t)(i0 + w * 32 + 16 + c) * DH);
  const h8* Qr1l = (const h8*)(Qlg + (size_t)(i0 + w * 32 + 16 + c) * DH);
  h8 q0h[2] = {Qr0h[g], Qr0h[4 + g]};
  h8 q0l[2] = {Qr0l[g], Qr0l[4 + g]};
  h8 q1h[2] = {Qr1h[g], Qr1h[4 + g]};
  h8 q1l[2] = {Qr1l[g], Qr1l[4 + g]};

  // K staging offsets (pre-swizzled global source, linear LDS dest)
  const int s0i = wu * 128 + lane;
  const int s1i = s0i + 64;
  const int ko0 = (s0i >> 3) * 128 + (((s0i & 7) ^ ((s0i >> 3) & 7)) << 4);
  const int ko1 = (s1i >> 3) * 128 + (((s1i & 7) ^ ((s1i >> 3) & 7)) << 4);

  // ---- stage rel tables: rel_h -> VB0 (32K), rel_w -> VB1 (40K) ----
  #pragma unroll
  for (int it = 0; it < 2; ++it) {
    int task = tid + it * 256;
    int oct = task & 7, s = task >> 3;
    int ss = s < 63 ? s : 62;
    const float* sh = rel_h + (size_t)ss * DH + oct * 8;
    const float* sw = rel_w + (size_t)ss * DH + oct * 8;
    h8 hh, ww;
    #pragma unroll
    for (int e = 0; e < 8; ++e) {
      hh[e] = (_Float16)sh[e];
      ww[e] = (_Float16)sw[e];
    }
    int byo = s * 128 + ((oct ^ (s & 7)) << 4);
    *(h8*)(SMem + 32768 + byo) = hh;
    *(h8*)(SMem + 40960 + byo) = ww;
  }
  __syncthreads();

  // ---- lh/lw tables via swapped 16x16 MFMA (lo folded into same acc) ----
  const int yi = (i0 + w * 32) >> 5;
  f4 zf = {0.f, 0.f, 0.f, 0.f};
  #pragma unroll
  for (int rs = 0; rs < 2; ++rs) {
    f4 lhD[4], lwD[4];
    #pragma unroll
    for (int st = 0; st < 4; ++st) { lhD[st] = zf; lwD[st] = zf; }
    #pragma unroll
    for (int kh = 0; kh < 2; ++kh) {
      h8 bq = rs ? q1h[kh] : q0h[kh];
      h8 bl = rs ? q1l[kh] : q0l[kh];
      #pragma unroll
      for (int st = 0; st < 4; ++st) {
        int srow = st * 16 + c;
        int chb = srow * 128 + (((kh * 4 + g) ^ (srow & 7)) << 4);
        h8 ra = *(const h8*)(SMem + 32768 + chb);
        h8 wa = *(const h8*)(SMem + 40960 + chb);
        lhD[st] = __builtin_amdgcn_mfma_f32_16x16x32_f16(ra, bq, lhD[st], 0, 0, 0);
        lhD[st] = __builtin_amdgcn_mfma_f32_16x16x32_f16(ra, bl, lhD[st], 0, 0, 0);
        lwD[st] = __builtin_amdgcn_mfma_f32_16x16x32_f16(wa, bq, lwD[st], 0, 0, 0);
        lwD[st] = __builtin_amdgcn_mfma_f32_16x16x32_f16(wa, bl, lwD[st], 0, 0, 0);
      }
    }
    int lrow = w * 32 + rs * 16 + c;
    #pragma unroll
    for (int st = 0; st < 4; ++st)
      #pragma unroll
      for (int reg = 0; reg < 4; ++reg) {
        int s = st * 16 + 4 * g + reg;
        int k = s - 31 + yi;
        if (k >= 0 && k < 32) LHt[lrow * 32 + k] = (_Float16)lhD[st][reg];
        LWT[lrow * 64 + s] = (_Float16)lwD[st][reg];
      }
  }
  __syncthreads();

  // lwp[reg]: lw[i][31 + jl(reg) - il]; lhreg[t]: lh[i][{2t,2t+1}] packed
  float lwp[16];
  unsigned lhreg[16];
  {
    int r = w * 32 + il;
    #pragma unroll
    for (int reg = 0; reg < 16; ++reg) {
      int jl = (reg & 3) + 8 * (reg >> 2) + 4 * hi;
      lwp[reg] = (float)LWT[r * 64 + 31 + jl - il];
    }
    #pragma unroll
    for (int t = 0; t < 16; ++t)
      lhreg[t] = *(const unsigned*)(LHt + r * 32 + 2 * t);
  }
  // main-loop Q fragments (32x32 B operand: col = il, k-slot = hi)
  const h8* Qmh = (const h8*)(Qhg + (size_t)(i0 + w * 32 + il) * DH);
  const h8* Qml = (const h8*)(Qlg + (size_t)(i0 + w * 32 + il) * DH);
  h8 qmh[4], qml[4];
  #pragma unroll
  for (int kb = 0; kb < 4; ++kb) {
    qmh[kb] = Qmh[2 * kb + hi];
    qml[kb] = Qml[2 * kb + hi];
  }
  __syncthreads();    // all LWT/LHt reads done before K/V overwrite

  // ---- stage tile 0 ----
  {
    gload_lds16((const char*)Khg + ko0, SMem + wu * 2048);
    gload_lds16((const char*)Khg + ko1, SMem + wu * 2048 + 1024);
    gload_lds16((const char*)Klg + ko0, SMem + 16384 + wu * 2048);
    gload_lds16((const char*)Klg + ko1, SMem + 16384 + wu * 2048 + 1024);
    const h8* vr = (const h8*)(Vg + (size_t)(2 * jp) * DH);
    h8 v0 = vr[dd], v1 = vr[8 + dd];
    us8 u0 = *(const us8*)&v0, u1 = *(const us8*)&v1;
    #pragma unroll
    for (int e = 0; e < 8; ++e) {
      int d = dd * 8 + e;
      unsigned val = (unsigned)u0[e] | ((unsigned)u1[e] << 16);
      *(unsigned*)(SMem + 32768 + d * 128 + (((jp >> 2) ^ (d & 7)) << 4) + (jp & 3) * 4) = val;
    }
  }
  __syncthreads();

  float m_s = -1e30f, lp = 0.f;
  f16v O0, O1;
  #pragma unroll
  for (int e = 0; e < 16; ++e) { O0[e] = 0.f; O1[e] = 0.f; }

  #pragma unroll
  for (int t = 0; t < 16; ++t) {
    char* Kc  = SMem + (t & 1) * 8192;
    char* KLc = SMem + 16384 + (t & 1) * 8192;
    char* Vc  = SMem + 32768 + (t & 1) * 8192;
    char* Kn  = SMem + ((t + 1) & 1) * 8192;
    char* KLn = SMem + 16384 + ((t + 1) & 1) * 8192;
    char* Vn  = SMem + 32768 + ((t + 1) & 1) * 8192;
    h8 v0 = {}, v1 = {};
    if (t < 15) {   // issue next-tile loads early (latency hides under QK)
      const char* kg  = (const char*)Khg + (size_t)(t + 1) * 8192;
      const char* klg = (const char*)Klg + (size_t)(t + 1) * 8192;
      gload_lds16(kg + ko0, Kn + wu * 2048);
      gload_lds16(kg + ko1, Kn + wu * 2048 + 1024);
      gload_lds16(klg + ko0, KLn + wu * 2048);
      gload_lds16(klg + ko1, KLn + wu * 2048 + 1024);
      const h8* vr = (const h8*)(Vg + (size_t)((t + 1) * 64 + 2 * jp) * DH);
      v0 = vr[dd];
      v1 = vr[8 + dd];
    }

    // ---- QK^T swapped 32x32x16 ----
    f16v S0, S1;
    #pragma unroll
    for (int e = 0; e < 16; ++e) { S0[e] = 0.f; S1[e] = 0.f; }
    #pragma unroll
    for (int kb = 0; kb < 4; ++kb) {
      int chb0 = il * 128 + (((2 * kb + hi) ^ swl) << 4);
      int chb1 = chb0 + 32 * 128;
      h8 a0h = *(const h8*)(Kc + chb0);
      h8 a0l = *(const h8*)(KLc + chb0);
      h8 a1h = *(const h8*)(Kc + chb1);
      h8 a1l = *(const h8*)(KLc + chb1);
      __builtin_amdgcn_s_setprio(1);
      S0 = __builtin_amdgcn_mfma_f32_32x32x16_f16(a0h, qmh[kb], S0, 0, 0, 0);
      S0 = __builtin_amdgcn_mfma_f32_32x32x16_f16(a0l, qmh[kb], S0, 0, 0, 0);
      S0 = __builtin_amdgcn_mfma_f32_32x32x16_f16(a0h, qml[kb], S0, 0, 0, 0);
      S1 = __builtin_amdgcn_mfma_f32_32x32x16_f16(a1h, qmh[kb], S1, 0, 0, 0);
      S1 = __builtin_amdgcn_mfma_f32_32x32x16_f16(a1l, qmh[kb], S1, 0, 0, 0);
      S1 = __builtin_amdgcn_mfma_f32_32x32x16_f16(a1h, qml[kb], S1, 0, 0, 0);
      __builtin_amdgcn_s_setprio(0);
    }

    // ---- finish: bias + online softmax + in-register P fragments ----
    h8 fr[4];
    {
      union { unsigned u; h2 h; } lu;
      lu.u = lhreg[t];
      float lh0 = (float)lu.h[0], lh1 = (float)lu.h[1];
      #pragma unroll
      for (int reg = 0; reg < 16; ++reg) {
        S0[reg] += lwp[reg] + lh0;
        S1[reg] += lwp[reg] + lh1;
      }
      float v8[8];
      #pragma unroll
      for (int e = 0; e < 8; ++e)
        v8[e] = fmaxf(fmaxf(S0[e], S0[e + 8]), fmaxf(S1[e], S1[e + 8]));
      float w0 = fmaxf(fmaxf(v8[0], v8[1]), fmaxf(v8[2], v8[3]));
      float w1 = fmaxf(fmaxf(v8[4], v8[5]), fmaxf(v8[6], v8[7]));
      float mx = fmaxf(w0, w1);
      mx = fmaxf(mx, __shfl_xor(mx, 32, 64));
      bool sk = mx <= m_s + DTHR;      // T13 defer-max
      if (!__all(sk)) {
        float mn = fmaxf(m_s, mx);
        float corr = fexp2(m_s - mn);
        m_s = mn;
        lp *= corr;
        #pragma unroll
        for (int e = 0; e < 16; ++e) { O0[e] *= corr; O1[e] *= corr; }
      }
      float pv0[16], pv1[16];
      #pragma unroll
      for (int e = 0; e < 16; ++e) {
        pv0[e] = fexp2(S0[e] - m_s);
        pv1[e] = fexp2(S1[e] - m_s);
      }
      f4 ps = zf;
      #pragma unroll
      for (int e = 0; e < 16; e += 4) {
        ps[0] += pv0[e] + pv1[e];
        ps[1] += pv0[e + 1] + pv1[e + 1];
        ps[2] += pv0[e + 2] + pv1[e + 2];
        ps[3] += pv0[e + 3] + pv1[e + 3];
      }
      lp += (ps[0] + ps[1]) + (ps[2] + ps[3]);
      #pragma unroll
      for (int jkb = 0; jkb < 4; ++jkb) {
        const float* pv = (jkb < 2) ? pv0 : pv1;
        int base = (jkb & 1) * 8;
        unsigned x01 = pk16(pv[base + 0], pv[base + 1]);
        unsigned x23 = pk16(pv[base + 2], pv[base + 3]);
        unsigned y01 = pk16(pv[base + 4], pv[base + 5]);
        unsigned y23 = pk16(pv[base + 6], pv[base + 7]);
        i2v r1 = __builtin_amdgcn_permlane32_swap((int)x01, (int)y01, false, false);
        i2v r2 = __builtin_amdgcn_permlane32_swap((int)x23, (int)y23, false, false);
        union { unsigned u[4]; h8 h; } fu;
        fu.u[0] = (unsigned)r1[0];
        fu.u[1] = (unsigned)r2[0];
        fu.u[2] = (unsigned)r1[1];
        fu.u[3] = (unsigned)r2[1];
        fr[jkb] = fu.h;
      }
    }

    // ---- PV swapped 32x32x16: A=V (LDS), B=P (registers) ----
    #pragma unroll
    for (int jkb = 0; jkb < 4; ++jkb) {
      int och = (((2 * jkb + hi) ^ swl) << 4);
      __builtin_amdgcn_s_setprio(1);
      h8 av0 = *(const h8*)(Vc + il * 128 + och);
      h8 av1 = *(const h8*)(Vc + (32 + il) * 128 + och);
      O0 = __builtin_amdgcn_mfma_f32_32x32x16_f16(av0, fr[jkb], O0, 0, 0, 0);
      O1 = __builtin_amdgcn_mfma_f32_32x32x16_f16(av1, fr[jkb], O1, 0, 0, 0);
      __builtin_amdgcn_s_setprio(0);
    }

    if (t < 15) {   // T14: write prefetched V after compute
      us8 u0 = *(const us8*)&v0, u1 = *(const us8*)&v1;
      #pragma unroll
      for (int e = 0; e < 8; ++e) {
        int d = dd * 8 + e;
        unsigned val = (unsigned)u0[e] | ((unsigned)u1[e] << 16);
        *(unsigned*)(Vn + d * 128 + (((jp >> 2) ^ (d & 7)) << 4) + (jp & 3) * 4) = val;
      }
    }
    __syncthreads();
  }

  // ---- epilogue: reduce l across hi, normalize, transpose, store ----
  float lt = lp + __shfl_xor(lp, 32, 64);
  float rr = __builtin_amdgcn_rcpf(lt);
  {
    int r = w * 32 + il;
    #pragma unroll
    for (int reg = 0; reg < 16; ++reg) {
      int dl = (reg & 3) + 8 * (reg >> 2) + 4 * hi;
      int d0 = dl;
      int d1 = 32 + dl;
      OT[d0 * 128 + (r ^ ((d0 & 7) << 3))] = O0[reg] * rr;
      OT[d1 * 128 + (r ^ ((d1 & 7) << 3))] = O1[reg] * rr;
    }
  }
  __syncthreads();
  #pragma unroll
  for (int it = 0; it < 8; ++it) {
    int task = tid + it * 256;
    int rq = task & 31, d = task >> 5;
    f4 vv = *(const f4*)&OT[d * 128 + ((rq * 4) ^ ((d & 7) << 3))];
    *(f4*)(out + (((size_t)bh * 64 + d) << 10) + i0 + rq * 4) = vv;
  }
}

extern "C" void kernel_launch(void* const* d_in, const int* in_sizes, int n_in,
                              void* d_out, int out_size, void* d_ws, size_t ws_size,
                              hipStream_t stream) {
  const float* x  = (const float*)d_in[0];
  const float* wq = (const float*)d_in[1];
  const float* rh = (const float*)d_in[2];
  const float* rw = (const float*)d_in[3];
  float* out = (float*)d_out;

  const size_t sz = (size_t)NBH * NPIX * DH;
  _Float16* Qh = (_Float16*)d_ws;
  _Float16* Ql = Qh + sz;
  _Float16* Kh = Ql + sz;
  _Float16* Kl = Kh + sz;
  _Float16* V  = Kl + sz;

  qkv_mfma<<<dim3(12, 16, 8), 256, 0, stream>>>(x, wq, Qh, Ql, Kh, Kl, V);
  attn_mfma<<<dim3(512), 256, 0, stream>>>(Qh, Ql, Kh, Kl, V, rh, rw, out);
}